// Round 10
// baseline (532.661 us; speedup 1.0000x reference)
//
#include <hip/hip_runtime.h>
#include <hip/hip_bf16.h>

#define HID 101
#define BATCH 1024
#define RPB 4
#define NBLK 256
#define NTHR 512
#define TSEQ 256

#define A1SZ  (7*4*4*512)    // 57344 halfs
#define A2SZ  (7*4*7*512)    // 100352 halfs
#define A2OFF A1SZ
#define AOOFF (A1SZ + A2SZ)  // 157696
#define AOSZ  (4*512)

typedef _Float16 h8 __attribute__((ext_vector_type(8)));
typedef _Float16 h4 __attribute__((ext_vector_type(4)));
typedef float f4 __attribute__((ext_vector_type(4)));

// ---------------------------------------------------------------------------
// Combined state vector (K=224, 7 k-tiles of 32):
//   k 0..100 : h1    k 101..103 : x    k 104 : one    k 112..212 : h2
// State LDS layout (bank-deconflicted): value for (k, col) stored at half-index
//   (k>>5)*512 + ((k>>3)&3)*160 + col*8 + (k&7),  col<4 only.
//   (q-groups at stride 160 halfs = 320B -> banks {0-15,16-31,0-15,16-31}: 2-way, free)
// A1 (L1, kt0..3): k<101->W_hh1[g][k]; 101..103->W_ih1; 104->b1; else 0.
// A2 (L2, kt0..6): k<101->W_ih2[g][k]; 104->b2; 112..212->W_hh2[g][k-112]; else 0.
// AO (out head, frags for kt3..6): row j<3: k 112..212 -> Wl[j][k-112]; else 0.
// Fragment: lane l holds A[row=l&15][k = kt*32 + ((l>>4)&3)*8 + i], i=0..7.
// ---------------------------------------------------------------------------
__global__ void prep_kernel(const float* __restrict__ W_ih1, const float* __restrict__ W_hh1,
                            const float* __restrict__ b_ih1, const float* __restrict__ b_hh1,
                            const float* __restrict__ W_ih2, const float* __restrict__ W_hh2,
                            const float* __restrict__ b_ih2, const float* __restrict__ b_hh2,
                            const float* __restrict__ Wl, _Float16* __restrict__ wsA) {
    int idx = blockIdx.x * blockDim.x + threadIdx.x;
    int stride = gridDim.x * blockDim.x;
    for (int t = idx; t < A1SZ; t += stride) {
        int i = t & 7, lane = (t >> 3) & 63, kt = (t >> 9) & 3, tau = (t >> 11) & 3, w = t >> 13;
        int k = kt * 32 + ((lane >> 4) & 3) * 8 + i;
        int u = 16 * w + (lane & 15);
        float v = 0.f;
        if (u < HID) {
            int g = tau * HID + u;
            if (k < HID) v = W_hh1[g * HID + k];
            else if (k >= 101 && k <= 103) v = W_ih1[g * 3 + (k - 101)];
            else if (k == 104) v = b_ih1[g] + b_hh1[g];
        }
        wsA[t] = (_Float16)v;
    }
    for (int t = idx; t < A2SZ; t += stride) {
        int i = t & 7, lane = (t >> 3) & 63;
        int rem = t >> 9;
        int kt = rem % 7; rem /= 7;
        int tau = rem & 3, w = rem >> 2;
        int k = kt * 32 + ((lane >> 4) & 3) * 8 + i;
        int u = 16 * w + (lane & 15);
        float v = 0.f;
        if (u < HID) {
            int g = tau * HID + u;
            if (k < HID) v = W_ih2[g * HID + k];
            else if (k == 104) v = b_ih2[g] + b_hh2[g];
            else if (k >= 112 && k < 213) v = W_hh2[g * HID + (k - 112)];
        }
        wsA[A2OFF + t] = (_Float16)v;
    }
    for (int t = idx; t < AOSZ; t += stride) {
        int i = t & 7, lane = (t >> 3) & 63, kk = (t >> 9) & 3;
        int k = (kk + 3) * 32 + ((lane >> 4) & 3) * 8 + i;
        int j = lane & 15;
        float v = (j < 3 && k >= 112 && k < 213) ? Wl[j * HID + (k - 112)] : 0.f;
        wsA[AOOFF + t] = (_Float16)v;
    }
}

__device__ __forceinline__ float sigm(float z) {
    return __builtin_amdgcn_rcpf(1.f + __expf(-z));
}
__device__ __forceinline__ float tanhf_(float z) {
    return 1.f - 2.f * __builtin_amdgcn_rcpf(__expf(2.f * z) + 1.f);
}

#define MFMA(acc, a, b) acc = __builtin_amdgcn_mfma_f32_16x16x32_f16(a, b, acc, 0, 0, 0)

// state slot for (k, col)
__device__ __forceinline__ int SLOT(int k, int col) {
    return (k >> 5) * 512 + ((k >> 3) & 3) * 160 + col * 8 + (k & 7);
}

// ---------------------------------------------------------------------------
// persistent kernel: 256 blocks x 512 thr (8 waves).
// Teacher-forced pipeline, ONE barrier per timestep:
//   stage(t): A(t) || B(t-1) || wave7: out(t-2) + stage x(t+1).
// Elementwise fully in-register (C-layout: lane 16q+col, elem e = unit 4q+e,
// batch col; the 4 gate accs tau=i,f,g,o are co-located per lane).
// h for 4 consecutive units packs into ONE ds_write_b64.
// ---------------------------------------------------------------------------
__global__ __launch_bounds__(NTHR, 2) void lstm_kernel(
    const float* __restrict__ input, const _Float16* __restrict__ wsA,
    const float* __restrict__ bl, int steps, float* __restrict__ out)
{
    const int tid = threadIdx.x;
    const int wid = tid >> 6, lane = tid & 63;
    const int q = lane >> 4, col = lane & 15;
    const int r0 = blockIdx.x * RPB;
    const int ostride = steps * 3;

    __shared__ _Float16 Sb[2][3584];       // combined state buffers
    __shared__ _Float16 xpre[TSEQ * 12];   // staged inputs (f16)

    // --- weights: volatile loads -> execute once, stay register-resident ---
    h8 A1[4][4];
    h8 A2[4][7];
    if (wid < 7) {
        #pragma unroll
        for (int tau = 0; tau < 4; tau++) {
            #pragma unroll
            for (int kt = 0; kt < 4; kt++)
                A1[tau][kt] = *(const volatile h8*)(
                    wsA + ((size_t)((wid * 4 + tau) * 4 + kt) * 512 + lane * 8));
            #pragma unroll
            for (int kt = 0; kt < 7; kt++)
                A2[tau][kt] = *(const volatile h8*)(
                    wsA + (size_t)A2OFF + ((size_t)((wid * 4 + tau) * 7 + kt) * 512 + lane * 8));
        }
    } else {
        #pragma unroll
        for (int kt = 0; kt < 4; kt++)
            A2[0][kt] = *(const volatile h8*)(
                wsA + (size_t)AOOFF + ((size_t)(kt) * 512 + lane * 8));
    }
    const float bl0 = bl[0], bl1 = bl[1], bl2 = bl[2];

    // lane geometry
    const int boff = q * 160 + col * 8;                 // swizzled B-frag offset
    const int uu0 = 16 * wid + 4 * q;                   // first unit of this lane's C-rows
    const int nv = HID - uu0;                           // valid units: >=4 full, 1 partial, <=0 none
    const int slot1 = SLOT(uu0, col);                   // h1 b64 slot (k=uu0, 4-half aligned)
    const int slot2 = SLOT(112 + uu0, col);             // h2 b64 slot
    const int xr = lane / 3, xj = lane - 3 * xr;        // wave7 lanes<12
    const int xoff = 1536 + xr * 8 + 5 + xj;            // x slot (k=101+xj, q=0)

    // ---- prologue ----
    for (int i2 = tid; i2 < 3584; i2 += NTHR) {
        Sb[0][i2] = (_Float16)0.f; Sb[1][i2] = (_Float16)0.f;
    }
    for (int g = tid; g < RPB * TSEQ * 3; g += NTHR) {
        int r = g / (TSEQ * 3), rem = g - r * (TSEQ * 3);
        int tt = rem / 3, j = rem - 3 * tt;
        xpre[tt * 12 + r * 3 + j] = (_Float16)input[(size_t)(r0 + r) * (TSEQ * 3) + rem];
    }
    __syncthreads();
    if (tid < 4) {   // bias-one slot k=104 (tile3, q=1), cols 0..3, both buffers
        Sb[0][1696 + tid * 8] = (_Float16)1.0f;
        Sb[1][1696 + tid * 8] = (_Float16)1.0f;
    }
    if (tid < 12) {  // x(0) -> S[0]
        int r = tid / 3, j = tid - 3 * (tid / 3);
        Sb[0][1536 + r * 8 + 5 + j] = xpre[r * 3 + j];
    }
    float c1e[4] = {0.f, 0.f, 0.f, 0.f}, c2e[4] = {0.f, 0.f, 0.f, 0.f};
    __syncthreads();

    // in-register elementwise + packed h store
    auto EWST = [&](const f4& a0, const f4& a1, const f4& a2, const f4& a3,
                    float* c, _Float16* dst, int slot) {
        float hv[4];
        #pragma unroll
        for (int e = 0; e < 4; e++) {
            float ig = sigm(a0[e]), fg = sigm(a1[e]), gg = tanhf_(a2[e]), og = sigm(a3[e]);
            c[e] = fg * c[e] + ig * gg;
            hv[e] = og * tanhf_(c[e]);
        }
        if (col < 4 && nv > 0) {
            if (nv >= 4) {
                h4 hp = { (_Float16)hv[0], (_Float16)hv[1], (_Float16)hv[2], (_Float16)hv[3] };
                *(h4*)(dst + slot) = hp;
            } else {
                dst[slot] = (_Float16)hv[0];   // wave6 q1: unit 100 only
            }
        }
    };

    // ---- teacher-forced pipeline: 1 barrier per step ----
    for (int t = 0; t < TSEQ; ++t) {
        _Float16* Rb = Sb[t & 1];
        _Float16* Wt = Sb[1 - (t & 1)];
        if (wid < 7) {
            h8 bf0 = (_Float16)0.f, bf1 = bf0, bf2 = bf0, bf3 = bf0,
               bf4 = bf0, bf5 = bf0, bf6 = bf0;
            if (col < 4) {
                bf0 = *(const h8*)(Rb + 0 * 512 + boff);
                bf1 = *(const h8*)(Rb + 1 * 512 + boff);
                bf2 = *(const h8*)(Rb + 2 * 512 + boff);
                bf3 = *(const h8*)(Rb + 3 * 512 + boff);
                bf4 = *(const h8*)(Rb + 4 * 512 + boff);
                bf5 = *(const h8*)(Rb + 5 * 512 + boff);
                bf6 = *(const h8*)(Rb + 6 * 512 + boff);
            }
            // ---- A(t): L1 over kt0..3 ----
            f4 a0 = {0.f,0.f,0.f,0.f}, a1 = a0, a2 = a0, a3 = a0;
            MFMA(a0, A1[0][0], bf0); MFMA(a1, A1[1][0], bf0); MFMA(a2, A1[2][0], bf0); MFMA(a3, A1[3][0], bf0);
            MFMA(a0, A1[0][1], bf1); MFMA(a1, A1[1][1], bf1); MFMA(a2, A1[2][1], bf1); MFMA(a3, A1[3][1], bf1);
            MFMA(a0, A1[0][2], bf2); MFMA(a1, A1[1][2], bf2); MFMA(a2, A1[2][2], bf2); MFMA(a3, A1[3][2], bf2);
            MFMA(a0, A1[0][3], bf3); MFMA(a1, A1[1][3], bf3); MFMA(a2, A1[2][3], bf3); MFMA(a3, A1[3][3], bf3);
            // ---- B(t-1): L2 over kt0..6 ----
            f4 b0 = {0.f,0.f,0.f,0.f}, b1 = b0, b2 = b0, b3 = b0;
            if (t >= 1) {
                MFMA(b0, A2[0][0], bf0); MFMA(b1, A2[1][0], bf0); MFMA(b2, A2[2][0], bf0); MFMA(b3, A2[3][0], bf0);
                MFMA(b0, A2[0][1], bf1); MFMA(b1, A2[1][1], bf1); MFMA(b2, A2[2][1], bf1); MFMA(b3, A2[3][1], bf1);
                MFMA(b0, A2[0][2], bf2); MFMA(b1, A2[1][2], bf2); MFMA(b2, A2[2][2], bf2); MFMA(b3, A2[3][2], bf2);
                MFMA(b0, A2[0][3], bf3); MFMA(b1, A2[1][3], bf3); MFMA(b2, A2[2][3], bf3); MFMA(b3, A2[3][3], bf3);
                MFMA(b0, A2[0][4], bf4); MFMA(b1, A2[1][4], bf4); MFMA(b2, A2[2][4], bf4); MFMA(b3, A2[3][4], bf4);
                MFMA(b0, A2[0][5], bf5); MFMA(b1, A2[1][5], bf5); MFMA(b2, A2[2][5], bf5); MFMA(b3, A2[3][5], bf5);
                MFMA(b0, A2[0][6], bf6); MFMA(b1, A2[1][6], bf6); MFMA(b2, A2[2][6], bf6); MFMA(b3, A2[3][6], bf6);
            }
            // ---- ew A -> h1(t) -> Wt ----
            EWST(a0, a1, a2, a3, c1e, Wt, slot1);
            // ---- ew B -> h2(t-1) -> Wt ----
            if (t >= 1) EWST(b0, b1, b2, b3, c2e, Wt, slot2);
        } else {
            // ---- wave 7: out(t-2) from Rb h2-region; stage x(t+1) -> Wt ----
            if (t >= 2) {
                f4 ao = {0.f, 0.f, 0.f, 0.f};
                #pragma unroll
                for (int kk = 0; kk < 4; kk++) {
                    h8 b = (_Float16)0.f;
                    if (col < 4) b = *(const h8*)(Rb + (kk + 3) * 512 + boff);
                    MFMA(ao, A2[0][kk], b);
                }
                if (lane < 4) {
                    float* op = out + (size_t)(r0 + lane) * ostride + (size_t)(t - 2) * 3;
                    op[0] = ao[0] + bl0; op[1] = ao[1] + bl1; op[2] = ao[2] + bl2;
                }
            }
            if (t + 1 < TSEQ && lane < 12)
                Wt[xoff] = xpre[(t + 1) * 12 + xr * 3 + xj];
        }
        __syncthreads();
    }

    // ---- drain stage: B(T-1) + out(T-2). reads S[0], h2(T-1) -> S[1] ----
    {
        _Float16* Rb = Sb[0];
        _Float16* Wt = Sb[1];
        if (wid < 7) {
            f4 b0 = {0.f,0.f,0.f,0.f}, b1 = b0, b2 = b0, b3 = b0;
            #pragma unroll
            for (int kt = 0; kt < 7; kt++) {
                h8 b = (_Float16)0.f;
                if (col < 4) b = *(const h8*)(Rb + kt * 512 + boff);
                MFMA(b0, A2[0][kt], b); MFMA(b1, A2[1][kt], b);
                MFMA(b2, A2[2][kt], b); MFMA(b3, A2[3][kt], b);
            }
            EWST(b0, b1, b2, b3, c2e, Wt, slot2);
        } else {
            f4 ao = {0.f, 0.f, 0.f, 0.f};
            #pragma unroll
            for (int kk = 0; kk < 4; kk++) {
                h8 b = (_Float16)0.f;
                if (col < 4) b = *(const h8*)(Rb + (kk + 3) * 512 + boff);
                MFMA(ao, A2[0][kk], b);
            }
            if (lane < 4) {
                float* op = out + (size_t)(r0 + lane) * ostride + (size_t)(TSEQ - 2) * 3;
                op[0] = ao[0] + bl0; op[1] = ao[1] + bl1; op[2] = ao[2] + bl2;
            }
        }
        __syncthreads();
    }

    // ---- future (autoregressive), serial 3-barrier steps ----
    for (int t = TSEQ; t < steps; ++t) {
        _Float16* R = Sb[t & 1];
        _Float16* W = Sb[1 - (t & 1)];
        // pre: wave7 out(t-1) from W h2-region; feedback x(t) -> R x-slots
        if (wid == 7) {
            f4 ao = {0.f, 0.f, 0.f, 0.f};
            #pragma unroll
            for (int kk = 0; kk < 4; kk++) {
                h8 b = (_Float16)0.f;
                if (col < 4) b = *(const h8*)(W + (kk + 3) * 512 + boff);
                MFMA(ao, A2[0][kk], b);
            }
            if (lane < 4) {
                float o0 = ao[0] + bl0, o1 = ao[1] + bl1, o2 = ao[2] + bl2;
                float* op = out + (size_t)(r0 + lane) * ostride + (size_t)(t - 1) * 3;
                op[0] = o0; op[1] = o1; op[2] = o2;
                R[1536 + lane * 8 + 5] = (_Float16)o0;
                R[1536 + lane * 8 + 6] = (_Float16)o1;
                R[1536 + lane * 8 + 7] = (_Float16)o2;
            }
        }
        __syncthreads();
        // A(t): read R kt0..3 -> h1(t) -> W
        if (wid < 7) {
            f4 a0 = {0.f,0.f,0.f,0.f}, a1 = a0, a2 = a0, a3 = a0;
            #pragma unroll
            for (int kt = 0; kt < 4; kt++) {
                h8 b = (_Float16)0.f;
                if (col < 4) b = *(const h8*)(R + kt * 512 + boff);
                MFMA(a0, A1[0][kt], b); MFMA(a1, A1[1][kt], b);
                MFMA(a2, A1[2][kt], b); MFMA(a3, A1[3][kt], b);
            }
            EWST(a0, a1, a2, a3, c1e, W, slot1);
        }
        __syncthreads();
        // B(t): read W kt0..6 (h1(t), h2(t-1)) -> h2(t) -> R
        if (wid < 7) {
            f4 b0 = {0.f,0.f,0.f,0.f}, b1 = b0, b2 = b0, b3 = b0;
            #pragma unroll
            for (int kt = 0; kt < 7; kt++) {
                h8 b = (_Float16)0.f;
                if (col < 4) b = *(const h8*)(W + kt * 512 + boff);
                MFMA(b0, A2[0][kt], b); MFMA(b1, A2[1][kt], b);
                MFMA(b2, A2[2][kt], b); MFMA(b3, A2[3][kt], b);
            }
            EWST(b0, b1, b2, b3, c2e, R, slot2);
        }
        __syncthreads();
    }

    // ---- epilogue: out(steps-1) from h2(steps-1) in Sb[1] ----
    if (wid == 7) {
        f4 ao = {0.f, 0.f, 0.f, 0.f};
        #pragma unroll
        for (int kk = 0; kk < 4; kk++) {
            h8 b = (_Float16)0.f;
            if (col < 4) b = *(const h8*)(&Sb[1][0] + (kk + 3) * 512 + boff);
            MFMA(ao, A2[0][kk], b);
        }
        if (lane < 4) {
            float* op = out + (size_t)(r0 + lane) * ostride + (size_t)(steps - 1) * 3;
            op[0] = ao[0] + bl0; op[1] = ao[1] + bl1; op[2] = ao[2] + bl2;
        }
    }
}

extern "C" void kernel_launch(void* const* d_in, const int* in_sizes, int n_in,
                              void* d_out, int out_size, void* d_ws, size_t ws_size,
                              hipStream_t stream) {
    const float* input = (const float*)d_in[0];
    const float* W_ih1 = (const float*)d_in[1];
    const float* W_hh1 = (const float*)d_in[2];
    const float* b_ih1 = (const float*)d_in[3];
    const float* b_hh1 = (const float*)d_in[4];
    const float* W_ih2 = (const float*)d_in[5];
    const float* W_hh2 = (const float*)d_in[6];
    const float* b_ih2 = (const float*)d_in[7];
    const float* b_hh2 = (const float*)d_in[8];
    const float* Wl    = (const float*)d_in[9];
    const float* bl    = (const float*)d_in[10];
    int steps = out_size / (BATCH * 3);       // 288
    _Float16* wsA = (_Float16*)d_ws;

    hipLaunchKernelGGL(prep_kernel, dim3(512), dim3(256), 0, stream,
                       W_ih1, W_hh1, b_ih1, b_hh1, W_ih2, W_hh2, b_ih2, b_hh2, Wl, wsA);
    hipLaunchKernelGGL(lstm_kernel, dim3(NBLK), dim3(NTHR), 0, stream,
                       input, wsA, bl, steps, (float*)d_out);
}

// Round 11
// 430.096 us; speedup vs baseline: 1.2385x; 1.2385x over previous
//
#include <hip/hip_runtime.h>
#include <hip/hip_bf16.h>

#define HID 101
#define BATCH 1024
#define RPB 4
#define NBLK 256
#define NTHR 512
#define TSEQ 256

#define A1SZ  (7*4*4*512)    // 57344 halfs
#define A2SZ  (7*4*7*512)    // 100352 halfs
#define A2OFF A1SZ
#define AOOFF (A1SZ + A2SZ)  // 157696
#define AOSZ  (4*512)

typedef _Float16 h8 __attribute__((ext_vector_type(8)));
typedef float f4 __attribute__((ext_vector_type(4)));

// ---------------------------------------------------------------------------
// Combined state vector (K=224, 7 k-tiles of 32):
//   k 0..100 : h1    k 101..103 : x    k 104 : one    k 112..212 : h2
// State LDS layout (bank-deconflicted, r10-proven): (k,col) at half-index
//   (k>>5)*512 + ((k>>3)&3)*160 + col*8 + (k&7),  col<4 only.
// A1 (L1, kt0..3): k<101->W_hh1[g][k]; 101..103->W_ih1; 104->b1; else 0.
// A2 (L2, kt0..6): k<101->W_ih2[g][k]; 104->b2; 112..212->W_hh2[g][k-112]; else 0.
// AO (out head, frags for kt3..6): row j<3: k 112..212 -> Wl[j][k-112]; else 0.
// Fragment: lane l holds A[row=l&15][k = kt*32 + ((l>>4)&3)*8 + i], i=0..7.
// ---------------------------------------------------------------------------
__global__ void prep_kernel(const float* __restrict__ W_ih1, const float* __restrict__ W_hh1,
                            const float* __restrict__ b_ih1, const float* __restrict__ b_hh1,
                            const float* __restrict__ W_ih2, const float* __restrict__ W_hh2,
                            const float* __restrict__ b_ih2, const float* __restrict__ b_hh2,
                            const float* __restrict__ Wl, _Float16* __restrict__ wsA) {
    int idx = blockIdx.x * blockDim.x + threadIdx.x;
    int stride = gridDim.x * blockDim.x;
    for (int t = idx; t < A1SZ; t += stride) {
        int i = t & 7, lane = (t >> 3) & 63, kt = (t >> 9) & 3, tau = (t >> 11) & 3, w = t >> 13;
        int k = kt * 32 + ((lane >> 4) & 3) * 8 + i;
        int u = 16 * w + (lane & 15);
        float v = 0.f;
        if (u < HID) {
            int g = tau * HID + u;
            if (k < HID) v = W_hh1[g * HID + k];
            else if (k >= 101 && k <= 103) v = W_ih1[g * 3 + (k - 101)];
            else if (k == 104) v = b_ih1[g] + b_hh1[g];
        }
        wsA[t] = (_Float16)v;
    }
    for (int t = idx; t < A2SZ; t += stride) {
        int i = t & 7, lane = (t >> 3) & 63;
        int rem = t >> 9;
        int kt = rem % 7; rem /= 7;
        int tau = rem & 3, w = rem >> 2;
        int k = kt * 32 + ((lane >> 4) & 3) * 8 + i;
        int u = 16 * w + (lane & 15);
        float v = 0.f;
        if (u < HID) {
            int g = tau * HID + u;
            if (k < HID) v = W_ih2[g * HID + k];
            else if (k == 104) v = b_ih2[g] + b_hh2[g];
            else if (k >= 112 && k < 213) v = W_hh2[g * HID + (k - 112)];
        }
        wsA[A2OFF + t] = (_Float16)v;
    }
    for (int t = idx; t < AOSZ; t += stride) {
        int i = t & 7, lane = (t >> 3) & 63, kk = (t >> 9) & 3;
        int k = (kk + 3) * 32 + ((lane >> 4) & 3) * 8 + i;
        int j = lane & 15;
        float v = (j < 3 && k >= 112 && k < 213) ? Wl[j * HID + (k - 112)] : 0.f;
        wsA[AOOFF + t] = (_Float16)v;
    }
}

__device__ __forceinline__ float sigm(float z) {
    return __builtin_amdgcn_rcpf(1.f + __expf(-z));
}
__device__ __forceinline__ float tanhf_(float z) {
    return 1.f - 2.f * __builtin_amdgcn_rcpf(__expf(2.f * z) + 1.f);
}
__device__ __forceinline__ unsigned short f16bits(_Float16 x) {
    return __builtin_bit_cast(unsigned short, x);
}

#define MFMA(acc, a, b) acc = __builtin_amdgcn_mfma_f32_16x16x32_f16(a, b, acc, 0, 0, 0)

// state slot for (k, col)
__device__ __forceinline__ int SLOT(int k, int col) {
    return (k >> 5) * 512 + ((k >> 3) & 3) * 160 + col * 8 + (k & 7);
}

// ---------------------------------------------------------------------------
// persistent kernel: 256 blocks x 512 thr (8 waves).
// Teacher-forced pipeline, ONE barrier per timestep:
//   stage(t): A(t) || B(t-1) || wave7: out(t-2) + stage x(t+1).
// Elementwise via zw exchange (1 unit/lane, all 64 lanes useful);
// packed b32 h-writes (shfl pair); conflict-free swizzled state layout;
// s_setprio(1) around MFMA clusters.
// ---------------------------------------------------------------------------
__global__ __launch_bounds__(NTHR, 2) void lstm_kernel(
    const float* __restrict__ input, const _Float16* __restrict__ wsA,
    const float* __restrict__ bl, int steps, float* __restrict__ out)
{
    const int tid = threadIdx.x;
    const int wid = tid >> 6, lane = tid & 63;
    const int q = lane >> 4, col = lane & 15;
    const int r0 = blockIdx.x * RPB;
    const int ostride = steps * 3;

    __shared__ _Float16 Sb[2][3584];       // combined state buffers
    __shared__ float zwA[7][4][4][16];     // L1 z exchange
    __shared__ float zwB[7][4][4][16];     // L2 z exchange
    __shared__ _Float16 xpre[TSEQ * 12];   // staged inputs (f16)

    // --- weights: volatile loads -> execute once, stay register-resident ---
    h8 A1[4][4];
    h8 A2[4][7];
    if (wid < 7) {
        #pragma unroll
        for (int tau = 0; tau < 4; tau++) {
            #pragma unroll
            for (int kt = 0; kt < 4; kt++)
                A1[tau][kt] = *(const volatile h8*)(
                    wsA + ((size_t)((wid * 4 + tau) * 4 + kt) * 512 + lane * 8));
            #pragma unroll
            for (int kt = 0; kt < 7; kt++)
                A2[tau][kt] = *(const volatile h8*)(
                    wsA + (size_t)A2OFF + ((size_t)((wid * 4 + tau) * 7 + kt) * 512 + lane * 8));
        }
    } else {
        #pragma unroll
        for (int kt = 0; kt < 4; kt++)
            A2[0][kt] = *(const volatile h8*)(
                wsA + (size_t)AOOFF + ((size_t)(kt) * 512 + lane * 8));
    }
    const float bl0 = bl[0], bl1 = bl[1], bl2 = bl[2];

    // lane geometry
    const int boff = q * 160 + col * 8;                 // swizzled B-frag offset
    const int r_ew = lane & 3, ul = lane >> 2;
    const int u = 16 * wid + ul;                        // this lane's ew unit
    const bool pairw = ((ul & 1) == 0) && (u + 1 <= 100);
    const bool lastw = (u == 100);
    const int slot1 = SLOT(u, r_ew);                    // h1 slot (k=u)
    const int slot2 = SLOT(112 + u, r_ew);              // h2 slot (k=112+u)
    const int xr = lane / 3, xj = lane - 3 * xr;        // wave7 lanes<12
    const int xoff = 1536 + xr * 8 + 5 + xj;            // x slot (k=101+xj)

    // ---- prologue ----
    for (int i2 = tid; i2 < 3584; i2 += NTHR) {
        Sb[0][i2] = (_Float16)0.f; Sb[1][i2] = (_Float16)0.f;
    }
    for (int g = tid; g < RPB * TSEQ * 3; g += NTHR) {
        int r = g / (TSEQ * 3), rem = g - r * (TSEQ * 3);
        int tt = rem / 3, j = rem - 3 * tt;
        xpre[tt * 12 + r * 3 + j] = (_Float16)input[(size_t)(r0 + r) * (TSEQ * 3) + rem];
    }
    __syncthreads();
    if (tid < 4) {   // bias-one slot k=104, both buffers
        Sb[0][1696 + tid * 8] = (_Float16)1.0f;
        Sb[1][1696 + tid * 8] = (_Float16)1.0f;
    }
    if (tid < 12) {  // x(0) -> S[0]
        int r = tid / 3, j = tid - 3 * (tid / 3);
        Sb[0][1536 + r * 8 + 5 + j] = xpre[r * 3 + j];
    }
    float c1 = 0.f, c2 = 0.f;
    __syncthreads();

    // ew for one layer: z from zw, update c, packed h store
    auto EWPACK = [&](const float* zwp, float& c, _Float16* dst, int slot) {
        float z0 = zwp[0 * 64 + r_ew * 16 + ul];
        float z1 = zwp[1 * 64 + r_ew * 16 + ul];
        float z2 = zwp[2 * 64 + r_ew * 16 + ul];
        float z3 = zwp[3 * 64 + r_ew * 16 + ul];
        float ig = sigm(z0), fg = sigm(z1), gg = tanhf_(z2), og = sigm(z3);
        c = fg * c + ig * gg;
        float hv = og * tanhf_(c);
        float hn = __shfl_down(hv, 4);
        if (pairw) {
            unsigned pk = (unsigned)f16bits((_Float16)hv) |
                          ((unsigned)f16bits((_Float16)hn) << 16);
            *(unsigned*)&dst[slot] = pk;
        } else if (lastw) {
            dst[slot] = (_Float16)hv;
        }
    };

    // ---- teacher-forced pipeline: 1 barrier per step ----
    for (int t = 0; t < TSEQ; ++t) {
        _Float16* Rb = Sb[t & 1];
        _Float16* Wt = Sb[1 - (t & 1)];
        if (wid < 7) {
            h8 bf0 = (_Float16)0.f, bf1 = bf0, bf2 = bf0, bf3 = bf0,
               bf4 = bf0, bf5 = bf0, bf6 = bf0;
            if (col < 4) {
                bf0 = *(const h8*)(Rb + 0 * 512 + boff);
                bf1 = *(const h8*)(Rb + 1 * 512 + boff);
                bf2 = *(const h8*)(Rb + 2 * 512 + boff);
                bf3 = *(const h8*)(Rb + 3 * 512 + boff);
                bf4 = *(const h8*)(Rb + 4 * 512 + boff);
                bf5 = *(const h8*)(Rb + 5 * 512 + boff);
                bf6 = *(const h8*)(Rb + 6 * 512 + boff);
            }
            __builtin_amdgcn_s_setprio(1);
            // ---- A(t): L1 over kt0..3 ----
            f4 a0 = {0.f,0.f,0.f,0.f}, a1 = a0, a2 = a0, a3 = a0;
            MFMA(a0, A1[0][0], bf0); MFMA(a1, A1[1][0], bf0); MFMA(a2, A1[2][0], bf0); MFMA(a3, A1[3][0], bf0);
            MFMA(a0, A1[0][1], bf1); MFMA(a1, A1[1][1], bf1); MFMA(a2, A1[2][1], bf1); MFMA(a3, A1[3][1], bf1);
            MFMA(a0, A1[0][2], bf2); MFMA(a1, A1[1][2], bf2); MFMA(a2, A1[2][2], bf2); MFMA(a3, A1[3][2], bf2);
            MFMA(a0, A1[0][3], bf3); MFMA(a1, A1[1][3], bf3); MFMA(a2, A1[2][3], bf3); MFMA(a3, A1[3][3], bf3);
            if (col < 4) {
                *(f4*)&zwA[wid][0][col][4 * q] = a0;
                *(f4*)&zwA[wid][1][col][4 * q] = a1;
                *(f4*)&zwA[wid][2][col][4 * q] = a2;
                *(f4*)&zwA[wid][3][col][4 * q] = a3;
            }
            // ---- B(t-1): L2 over kt0..6 (covers zwA store->load latency) ----
            if (t >= 1) {
                f4 b0 = {0.f,0.f,0.f,0.f}, b1 = b0, b2 = b0, b3 = b0;
                MFMA(b0, A2[0][0], bf0); MFMA(b1, A2[1][0], bf0); MFMA(b2, A2[2][0], bf0); MFMA(b3, A2[3][0], bf0);
                MFMA(b0, A2[0][1], bf1); MFMA(b1, A2[1][1], bf1); MFMA(b2, A2[2][1], bf1); MFMA(b3, A2[3][1], bf1);
                MFMA(b0, A2[0][2], bf2); MFMA(b1, A2[1][2], bf2); MFMA(b2, A2[2][2], bf2); MFMA(b3, A2[3][2], bf2);
                MFMA(b0, A2[0][3], bf3); MFMA(b1, A2[1][3], bf3); MFMA(b2, A2[2][3], bf3); MFMA(b3, A2[3][3], bf3);
                MFMA(b0, A2[0][4], bf4); MFMA(b1, A2[1][4], bf4); MFMA(b2, A2[2][4], bf4); MFMA(b3, A2[3][4], bf4);
                MFMA(b0, A2[0][5], bf5); MFMA(b1, A2[1][5], bf5); MFMA(b2, A2[2][5], bf5); MFMA(b3, A2[3][5], bf5);
                MFMA(b0, A2[0][6], bf6); MFMA(b1, A2[1][6], bf6); MFMA(b2, A2[2][6], bf6); MFMA(b3, A2[3][6], bf6);
                if (col < 4) {
                    *(f4*)&zwB[wid][0][col][4 * q] = b0;
                    *(f4*)&zwB[wid][1][col][4 * q] = b1;
                    *(f4*)&zwB[wid][2][col][4 * q] = b2;
                    *(f4*)&zwB[wid][3][col][4 * q] = b3;
                }
            }
            __builtin_amdgcn_s_setprio(0);
            // ---- ew A -> h1(t) -> Wt ; ew B -> h2(t-1) -> Wt ----
            EWPACK(&zwA[wid][0][0][0], c1, Wt, slot1);
            if (t >= 1) EWPACK(&zwB[wid][0][0][0], c2, Wt, slot2);
        } else {
            // ---- wave 7: out(t-2) from Rb h2-region; stage x(t+1) -> Wt ----
            if (t >= 2) {
                f4 ao = {0.f, 0.f, 0.f, 0.f};
                __builtin_amdgcn_s_setprio(1);
                #pragma unroll
                for (int kk = 0; kk < 4; kk++) {
                    h8 b = (_Float16)0.f;
                    if (col < 4) b = *(const h8*)(Rb + (kk + 3) * 512 + boff);
                    MFMA(ao, A2[0][kk], b);
                }
                __builtin_amdgcn_s_setprio(0);
                if (lane < 4) {
                    float* op = out + (size_t)(r0 + lane) * ostride + (size_t)(t - 2) * 3;
                    op[0] = ao[0] + bl0; op[1] = ao[1] + bl1; op[2] = ao[2] + bl2;
                }
            }
            if (t + 1 < TSEQ && lane < 12)
                Wt[xoff] = xpre[(t + 1) * 12 + xr * 3 + xj];
        }
        __syncthreads();
    }

    // ---- drain stage: B(T-1) + out(T-2). reads S[0], h2(T-1) -> S[1] ----
    {
        _Float16* Rb = Sb[0];
        _Float16* Wt = Sb[1];
        if (wid < 7) {
            f4 b0 = {0.f,0.f,0.f,0.f}, b1 = b0, b2 = b0, b3 = b0;
            #pragma unroll
            for (int kt = 0; kt < 7; kt++) {
                h8 b = (_Float16)0.f;
                if (col < 4) b = *(const h8*)(Rb + kt * 512 + boff);
                MFMA(b0, A2[0][kt], b); MFMA(b1, A2[1][kt], b);
                MFMA(b2, A2[2][kt], b); MFMA(b3, A2[3][kt], b);
            }
            if (col < 4) {
                *(f4*)&zwB[wid][0][col][4 * q] = b0;
                *(f4*)&zwB[wid][1][col][4 * q] = b1;
                *(f4*)&zwB[wid][2][col][4 * q] = b2;
                *(f4*)&zwB[wid][3][col][4 * q] = b3;
            }
            EWPACK(&zwB[wid][0][0][0], c2, Wt, slot2);
        } else {
            f4 ao = {0.f, 0.f, 0.f, 0.f};
            #pragma unroll
            for (int kk = 0; kk < 4; kk++) {
                h8 b = (_Float16)0.f;
                if (col < 4) b = *(const h8*)(Rb + (kk + 3) * 512 + boff);
                MFMA(ao, A2[0][kk], b);
            }
            if (lane < 4) {
                float* op = out + (size_t)(r0 + lane) * ostride + (size_t)(TSEQ - 2) * 3;
                op[0] = ao[0] + bl0; op[1] = ao[1] + bl1; op[2] = ao[2] + bl2;
            }
        }
        __syncthreads();
    }

    // ---- future (autoregressive), serial 3-barrier steps ----
    for (int t = TSEQ; t < steps; ++t) {
        _Float16* R = Sb[t & 1];
        _Float16* W = Sb[1 - (t & 1)];
        // pre: wave7 out(t-1) from W h2-region; feedback x(t) -> R x-slots
        if (wid == 7) {
            f4 ao = {0.f, 0.f, 0.f, 0.f};
            #pragma unroll
            for (int kk = 0; kk < 4; kk++) {
                h8 b = (_Float16)0.f;
                if (col < 4) b = *(const h8*)(W + (kk + 3) * 512 + boff);
                MFMA(ao, A2[0][kk], b);
            }
            if (lane < 4) {
                float o0 = ao[0] + bl0, o1 = ao[1] + bl1, o2 = ao[2] + bl2;
                float* op = out + (size_t)(r0 + lane) * ostride + (size_t)(t - 1) * 3;
                op[0] = o0; op[1] = o1; op[2] = o2;
                R[1536 + lane * 8 + 5] = (_Float16)o0;
                R[1536 + lane * 8 + 6] = (_Float16)o1;
                R[1536 + lane * 8 + 7] = (_Float16)o2;
            }
        }
        __syncthreads();
        // A(t): read R kt0..3 -> h1(t) -> W
        if (wid < 7) {
            f4 a0 = {0.f,0.f,0.f,0.f}, a1 = a0, a2 = a0, a3 = a0;
            #pragma unroll
            for (int kt = 0; kt < 4; kt++) {
                h8 b = (_Float16)0.f;
                if (col < 4) b = *(const h8*)(R + kt * 512 + boff);
                MFMA(a0, A1[0][kt], b); MFMA(a1, A1[1][kt], b);
                MFMA(a2, A1[2][kt], b); MFMA(a3, A1[3][kt], b);
            }
            if (col < 4) {
                *(f4*)&zwA[wid][0][col][4 * q] = a0;
                *(f4*)&zwA[wid][1][col][4 * q] = a1;
                *(f4*)&zwA[wid][2][col][4 * q] = a2;
                *(f4*)&zwA[wid][3][col][4 * q] = a3;
            }
            EWPACK(&zwA[wid][0][0][0], c1, W, slot1);
        }
        __syncthreads();
        // B(t): read W kt0..6 (h1(t), h2(t-1)) -> h2(t) -> R
        if (wid < 7) {
            f4 b0 = {0.f,0.f,0.f,0.f}, b1 = b0, b2 = b0, b3 = b0;
            #pragma unroll
            for (int kt = 0; kt < 7; kt++) {
                h8 b = (_Float16)0.f;
                if (col < 4) b = *(const h8*)(W + kt * 512 + boff);
                MFMA(b0, A2[0][kt], b); MFMA(b1, A2[1][kt], b);
                MFMA(b2, A2[2][kt], b); MFMA(b3, A2[3][kt], b);
            }
            if (col < 4) {
                *(f4*)&zwB[wid][0][col][4 * q] = b0;
                *(f4*)&zwB[wid][1][col][4 * q] = b1;
                *(f4*)&zwB[wid][2][col][4 * q] = b2;
                *(f4*)&zwB[wid][3][col][4 * q] = b3;
            }
            EWPACK(&zwB[wid][0][0][0], c2, R, slot2);
        }
        __syncthreads();
    }

    // ---- epilogue: out(steps-1) from h2(steps-1) in Sb[1] ----
    if (wid == 7) {
        f4 ao = {0.f, 0.f, 0.f, 0.f};
        #pragma unroll
        for (int kk = 0; kk < 4; kk++) {
            h8 b = (_Float16)0.f;
            if (col < 4) b = *(const h8*)(&Sb[1][0] + (kk + 3) * 512 + boff);
            MFMA(ao, A2[0][kk], b);
        }
        if (lane < 4) {
            float* op = out + (size_t)(r0 + lane) * ostride + (size_t)(steps - 1) * 3;
            op[0] = ao[0] + bl0; op[1] = ao[1] + bl1; op[2] = ao[2] + bl2;
        }
    }
}

extern "C" void kernel_launch(void* const* d_in, const int* in_sizes, int n_in,
                              void* d_out, int out_size, void* d_ws, size_t ws_size,
                              hipStream_t stream) {
    const float* input = (const float*)d_in[0];
    const float* W_ih1 = (const float*)d_in[1];
    const float* W_hh1 = (const float*)d_in[2];
    const float* b_ih1 = (const float*)d_in[3];
    const float* b_hh1 = (const float*)d_in[4];
    const float* W_ih2 = (const float*)d_in[5];
    const float* W_hh2 = (const float*)d_in[6];
    const float* b_ih2 = (const float*)d_in[7];
    const float* b_hh2 = (const float*)d_in[8];
    const float* Wl    = (const float*)d_in[9];
    const float* bl    = (const float*)d_in[10];
    int steps = out_size / (BATCH * 3);       // 288
    _Float16* wsA = (_Float16*)d_ws;

    hipLaunchKernelGGL(prep_kernel, dim3(512), dim3(256), 0, stream,
                       W_ih1, W_hh1, b_ih1, b_hh1, W_ih2, W_hh2, b_ih2, b_hh2, Wl, wsA);
    hipLaunchKernelGGL(lstm_kernel, dim3(NBLK), dim3(NTHR), 0, stream,
                       input, wsA, bl, steps, (float*)d_out);
}

// Round 13
// 425.393 us; speedup vs baseline: 1.2522x; 1.0111x over previous
//
#include <hip/hip_runtime.h>
#include <hip/hip_bf16.h>

#define HID 101
#define BATCH 1024
#define RPB 4
#define NBLK 256
#define NTHR 512
#define TSEQ 256

#define A1SZ  (7*4*4*512)    // 57344 halfs
#define A2SZ  (7*4*7*512)    // 100352 halfs
#define A2OFF A1SZ
#define AOOFF (A1SZ + A2SZ)  // 157696
#define AOSZ  (4*512)

typedef _Float16 h8 __attribute__((ext_vector_type(8)));
typedef float f4 __attribute__((ext_vector_type(4)));

// ---------------------------------------------------------------------------
// Combined state vector (K=224, 7 k-tiles of 32):
//   k 0..100 : h1    k 101..103 : x    k 104 : one    k 112..212 : h2
// A1 (L1, kt0..3): k<101->W_hh1[g][k]; 101..103->W_ih1; 104->b1; else 0.
// A2 (L2, kt0..6): k<101->W_ih2[g][k]; 104->b2; 112..212->W_hh2[g][k-112]; else 0.
// AO (out head, frags for kt3..6): row j<3: k 112..212 -> Wl[j][k-112]; else 0.
// Fragment: lane l holds A[row=l&15][k = kt*32 + ((l>>4)&3)*8 + i], i=0..7.
// ---------------------------------------------------------------------------
__global__ void prep_kernel(const float* __restrict__ W_ih1, const float* __restrict__ W_hh1,
                            const float* __restrict__ b_ih1, const float* __restrict__ b_hh1,
                            const float* __restrict__ W_ih2, const float* __restrict__ W_hh2,
                            const float* __restrict__ b_ih2, const float* __restrict__ b_hh2,
                            const float* __restrict__ Wl, _Float16* __restrict__ wsA) {
    int idx = blockIdx.x * blockDim.x + threadIdx.x;
    int stride = gridDim.x * blockDim.x;
    for (int t = idx; t < A1SZ; t += stride) {
        int i = t & 7, lane = (t >> 3) & 63, kt = (t >> 9) & 3, tau = (t >> 11) & 3, w = t >> 13;
        int k = kt * 32 + ((lane >> 4) & 3) * 8 + i;
        int u = 16 * w + (lane & 15);
        float v = 0.f;
        if (u < HID) {
            int g = tau * HID + u;
            if (k < HID) v = W_hh1[g * HID + k];
            else if (k >= 101 && k <= 103) v = W_ih1[g * 3 + (k - 101)];
            else if (k == 104) v = b_ih1[g] + b_hh1[g];
        }
        wsA[t] = (_Float16)v;
    }
    for (int t = idx; t < A2SZ; t += stride) {
        int i = t & 7, lane = (t >> 3) & 63;
        int rem = t >> 9;
        int kt = rem % 7; rem /= 7;
        int tau = rem & 3, w = rem >> 2;
        int k = kt * 32 + ((lane >> 4) & 3) * 8 + i;
        int u = 16 * w + (lane & 15);
        float v = 0.f;
        if (u < HID) {
            int g = tau * HID + u;
            if (k < HID) v = W_ih2[g * HID + k];
            else if (k == 104) v = b_ih2[g] + b_hh2[g];
            else if (k >= 112 && k < 213) v = W_hh2[g * HID + (k - 112)];
        }
        wsA[A2OFF + t] = (_Float16)v;
    }
    for (int t = idx; t < AOSZ; t += stride) {
        int i = t & 7, lane = (t >> 3) & 63, kk = (t >> 9) & 3;
        int k = (kk + 3) * 32 + ((lane >> 4) & 3) * 8 + i;
        int j = lane & 15;
        float v = (j < 3 && k >= 112 && k < 213) ? Wl[j * HID + (k - 112)] : 0.f;
        wsA[AOOFF + t] = (_Float16)v;
    }
}

__device__ __forceinline__ float sigm(float z) {
    return __builtin_amdgcn_rcpf(1.f + __expf(-z));
}
__device__ __forceinline__ float tanhf_(float z) {
    return 1.f - 2.f * __builtin_amdgcn_rcpf(__expf(2.f * z) + 1.f);
}

#define MFMA(acc, a, b) acc = __builtin_amdgcn_mfma_f32_16x16x32_f16(a, b, acc, 0, 0, 0)

// ---------------------------------------------------------------------------
// persistent kernel: 256 blocks x 512 thr (8 waves).
// Teacher-forced pipeline, ONE barrier per timestep:
//   stage(t): A(t) [needs h1(t-1),x(t)] || B(t-1) [needs h1(t-1),h2(t-2)]
//             || wave7: out(t-2) + stage x(t+1).
//   All reads from S[t&1]; all writes to S[1-(t&1)].
// Future steps: serial 3-barrier shape (feedback dependency).
// ---------------------------------------------------------------------------
__global__ __launch_bounds__(NTHR, 2) void lstm_kernel(
    const float* __restrict__ input, const _Float16* __restrict__ wsA,
    const float* __restrict__ bl, int steps, float* __restrict__ out)
{
    const int tid = threadIdx.x;
    const int wid = tid >> 6, lane = tid & 63;
    const int q = lane >> 4, col = lane & 15;
    const int r0 = blockIdx.x * RPB;
    const int ostride = steps * 3;

    __shared__ _Float16 Sb[2][3584];       // combined state buffers
    __shared__ float zwA[7][4][4][16];     // L1 z exchange
    __shared__ float zwB[7][4][4][16];     // L2 z exchange
    __shared__ _Float16 xpre[TSEQ * 12];   // staged inputs (f16)

    // --- weights: volatile loads -> execute once, stay register-resident ---
    h8 A1[4][4];
    h8 A2[4][7];
    if (wid < 7) {
        #pragma unroll
        for (int tau = 0; tau < 4; tau++) {
            #pragma unroll
            for (int kt = 0; kt < 4; kt++)
                A1[tau][kt] = *(const volatile h8*)(
                    wsA + ((size_t)((wid * 4 + tau) * 4 + kt) * 512 + lane * 8));
            #pragma unroll
            for (int kt = 0; kt < 7; kt++)
                A2[tau][kt] = *(const volatile h8*)(
                    wsA + (size_t)A2OFF + ((size_t)((wid * 4 + tau) * 7 + kt) * 512 + lane * 8));
        }
    } else {
        #pragma unroll
        for (int kt = 0; kt < 4; kt++)
            A2[0][kt] = *(const volatile h8*)(
                wsA + (size_t)AOOFF + ((size_t)(kt) * 512 + lane * 8));
    }
    const float bl0 = bl[0], bl1 = bl[1], bl2 = bl[2];

    // lane geometry
    const int r_ew = lane & 3, ul = lane >> 2;
    const int u = 16 * wid + ul;
    const bool ewv = (wid < 7) && (u < HID);
    const int slot1 = (u >> 3) * 128 + r_ew * 8 + (u & 7);           // h1 slot (k=u)
    const int slot2 = (14 + (u >> 3)) * 128 + r_ew * 8 + (u & 7);    // h2 slot (k=112+u)
    const int boff = q * 128 + col * 8;
    const int xr = lane / 3, xj = lane - 3 * xr;                     // wave7 lanes<12
    const int xoff = 12 * 128 + xr * 8 + 5 + xj;                     // x slot (k=101+xj)

    // ---- prologue ----
    for (int i2 = tid; i2 < 3584; i2 += NTHR) {
        Sb[0][i2] = (_Float16)0.f; Sb[1][i2] = (_Float16)0.f;
    }
    for (int g = tid; g < RPB * TSEQ * 3; g += NTHR) {
        int r = g / (TSEQ * 3), rem = g - r * (TSEQ * 3);
        int tt = rem / 3, j = rem - 3 * tt;
        xpre[tt * 12 + r * 3 + j] = (_Float16)input[(size_t)(r0 + r) * (TSEQ * 3) + rem];
    }
    __syncthreads();
    if (tid < 16) {   // bias-one slot k=104, both buffers
        Sb[0][13 * 128 + tid * 8] = (_Float16)1.0f;
        Sb[1][13 * 128 + tid * 8] = (_Float16)1.0f;
    }
    if (tid < 12) {  // x(0) -> S[0]
        int r = tid / 3, j = tid - 3 * (tid / 3);
        Sb[0][12 * 128 + r * 8 + 5 + j] = xpre[r * 3 + j];
    }
    float c1 = 0.f, c2 = 0.f;
    __syncthreads();

    // ---- teacher-forced pipeline: 1 barrier per step ----
    for (int t = 0; t < TSEQ; ++t) {
        _Float16* Rb = Sb[t & 1];
        _Float16* Wt = Sb[1 - (t & 1)];
        if (wid < 7) {
            // shared B-fragments (kt0..6) of S[p]
            h8 bf0 = *(const h8*)(Rb + 0 * 512 + boff);
            h8 bf1 = *(const h8*)(Rb + 1 * 512 + boff);
            h8 bf2 = *(const h8*)(Rb + 2 * 512 + boff);
            h8 bf3 = *(const h8*)(Rb + 3 * 512 + boff);
            h8 bf4 = *(const h8*)(Rb + 4 * 512 + boff);
            h8 bf5 = *(const h8*)(Rb + 5 * 512 + boff);
            h8 bf6 = *(const h8*)(Rb + 6 * 512 + boff);
            // ---- A(t): L1 over kt0..3 ----
            f4 a0 = {0.f,0.f,0.f,0.f}, a1 = a0, a2 = a0, a3 = a0;
            MFMA(a0, A1[0][0], bf0); MFMA(a1, A1[1][0], bf0); MFMA(a2, A1[2][0], bf0); MFMA(a3, A1[3][0], bf0);
            MFMA(a0, A1[0][1], bf1); MFMA(a1, A1[1][1], bf1); MFMA(a2, A1[2][1], bf1); MFMA(a3, A1[3][1], bf1);
            MFMA(a0, A1[0][2], bf2); MFMA(a1, A1[1][2], bf2); MFMA(a2, A1[2][2], bf2); MFMA(a3, A1[3][2], bf2);
            MFMA(a0, A1[0][3], bf3); MFMA(a1, A1[1][3], bf3); MFMA(a2, A1[2][3], bf3); MFMA(a3, A1[3][3], bf3);
            if (col < 4) {
                *(f4*)&zwA[wid][0][col][4 * q] = a0;
                *(f4*)&zwA[wid][1][col][4 * q] = a1;
                *(f4*)&zwA[wid][2][col][4 * q] = a2;
                *(f4*)&zwA[wid][3][col][4 * q] = a3;
            }
            // ---- B(t-1): L2 over kt0..6 ----
            if (t >= 1) {
                f4 b0 = {0.f,0.f,0.f,0.f}, b1 = b0, b2 = b0, b3 = b0;
                MFMA(b0, A2[0][0], bf0); MFMA(b1, A2[1][0], bf0); MFMA(b2, A2[2][0], bf0); MFMA(b3, A2[3][0], bf0);
                MFMA(b0, A2[0][1], bf1); MFMA(b1, A2[1][1], bf1); MFMA(b2, A2[2][1], bf1); MFMA(b3, A2[3][1], bf1);
                MFMA(b0, A2[0][2], bf2); MFMA(b1, A2[1][2], bf2); MFMA(b2, A2[2][2], bf2); MFMA(b3, A2[3][2], bf2);
                MFMA(b0, A2[0][3], bf3); MFMA(b1, A2[1][3], bf3); MFMA(b2, A2[2][3], bf3); MFMA(b3, A2[3][3], bf3);
                MFMA(b0, A2[0][4], bf4); MFMA(b1, A2[1][4], bf4); MFMA(b2, A2[2][4], bf4); MFMA(b3, A2[3][4], bf4);
                MFMA(b0, A2[0][5], bf5); MFMA(b1, A2[1][5], bf5); MFMA(b2, A2[2][5], bf5); MFMA(b3, A2[3][5], bf5);
                MFMA(b0, A2[0][6], bf6); MFMA(b1, A2[1][6], bf6); MFMA(b2, A2[2][6], bf6); MFMA(b3, A2[3][6], bf6);
                if (col < 4) {
                    *(f4*)&zwB[wid][0][col][4 * q] = b0;
                    *(f4*)&zwB[wid][1][col][4 * q] = b1;
                    *(f4*)&zwB[wid][2][col][4 * q] = b2;
                    *(f4*)&zwB[wid][3][col][4 * q] = b3;
                }
            }
            // ---- ew A -> h1(t) -> Wt ----
            {
                float z0 = zwA[wid][0][r_ew][ul], z1 = zwA[wid][1][r_ew][ul];
                float z2 = zwA[wid][2][r_ew][ul], z3 = zwA[wid][3][r_ew][ul];
                float ig = sigm(z0), fg = sigm(z1), gg = tanhf_(z2), og = sigm(z3);
                c1 = fg * c1 + ig * gg;
                float h1v = og * tanhf_(c1);
                if (ewv) Wt[slot1] = (_Float16)h1v;
            }
            // ---- ew B -> h2(t-1) -> Wt ----
            if (t >= 1) {
                float z0 = zwB[wid][0][r_ew][ul], z1 = zwB[wid][1][r_ew][ul];
                float z2 = zwB[wid][2][r_ew][ul], z3 = zwB[wid][3][r_ew][ul];
                float ig = sigm(z0), fg = sigm(z1), gg = tanhf_(z2), og = sigm(z3);
                c2 = fg * c2 + ig * gg;
                float h2v = og * tanhf_(c2);
                if (ewv) Wt[slot2] = (_Float16)h2v;
            }
        } else {
            // ---- wave 7: out(t-2) from Rb h2-region; stage x(t+1) -> Wt ----
            if (t >= 2) {
                f4 ao = {0.f, 0.f, 0.f, 0.f};
                #pragma unroll
                for (int kk = 0; kk < 4; kk++) {
                    h8 b = (_Float16)0.f;
                    if (col < 4) b = *(const h8*)(Rb + (kk + 3) * 512 + boff);
                    MFMA(ao, A2[0][kk], b);
                }
                if (lane < 4) {
                    float* op = out + (size_t)(r0 + lane) * ostride + (size_t)(t - 2) * 3;
                    op[0] = ao[0] + bl0; op[1] = ao[1] + bl1; op[2] = ao[2] + bl2;
                }
            }
            if (t + 1 < TSEQ && lane < 12)
                Wt[xoff] = xpre[(t + 1) * 12 + xr * 3 + xj];
        }
        __syncthreads();
    }

    // ---- drain stage (t=TSEQ): B(T-1) + out(T-2). reads S[0], h2(T-1)->S[1] ----
    {
        _Float16* Rb = Sb[0];
        _Float16* Wt = Sb[1];
        if (wid < 7) {
            h8 bf0 = *(const h8*)(Rb + 0 * 512 + boff);
            h8 bf1 = *(const h8*)(Rb + 1 * 512 + boff);
            h8 bf2 = *(const h8*)(Rb + 2 * 512 + boff);
            h8 bf3 = *(const h8*)(Rb + 3 * 512 + boff);
            h8 bf4 = *(const h8*)(Rb + 4 * 512 + boff);
            h8 bf5 = *(const h8*)(Rb + 5 * 512 + boff);
            h8 bf6 = *(const h8*)(Rb + 6 * 512 + boff);
            f4 b0 = {0.f,0.f,0.f,0.f}, b1 = b0, b2 = b0, b3 = b0;
            MFMA(b0, A2[0][0], bf0); MFMA(b1, A2[1][0], bf0); MFMA(b2, A2[2][0], bf0); MFMA(b3, A2[3][0], bf0);
            MFMA(b0, A2[0][1], bf1); MFMA(b1, A2[1][1], bf1); MFMA(b2, A2[2][1], bf1); MFMA(b3, A2[3][1], bf1);
            MFMA(b0, A2[0][2], bf2); MFMA(b1, A2[1][2], bf2); MFMA(b2, A2[2][2], bf2); MFMA(b3, A2[3][2], bf2);
            MFMA(b0, A2[0][3], bf3); MFMA(b1, A2[1][3], bf3); MFMA(b2, A2[2][3], bf3); MFMA(b3, A2[3][3], bf3);
            MFMA(b0, A2[0][4], bf4); MFMA(b1, A2[1][4], bf4); MFMA(b2, A2[2][4], bf4); MFMA(b3, A2[3][4], bf4);
            MFMA(b0, A2[0][5], bf5); MFMA(b1, A2[1][5], bf5); MFMA(b2, A2[2][5], bf5); MFMA(b3, A2[3][5], bf5);
            MFMA(b0, A2[0][6], bf6); MFMA(b1, A2[1][6], bf6); MFMA(b2, A2[2][6], bf6); MFMA(b3, A2[3][6], bf6);
            if (col < 4) {
                *(f4*)&zwB[wid][0][col][4 * q] = b0;
                *(f4*)&zwB[wid][1][col][4 * q] = b1;
                *(f4*)&zwB[wid][2][col][4 * q] = b2;
                *(f4*)&zwB[wid][3][col][4 * q] = b3;
            }
            float z0 = zwB[wid][0][r_ew][ul], z1 = zwB[wid][1][r_ew][ul];
            float z2 = zwB[wid][2][r_ew][ul], z3 = zwB[wid][3][r_ew][ul];
            float ig = sigm(z0), fg = sigm(z1), gg = tanhf_(z2), og = sigm(z3);
            c2 = fg * c2 + ig * gg;
            float h2v = og * tanhf_(c2);
            if (ewv) Wt[slot2] = (_Float16)h2v;
        } else {
            f4 ao = {0.f, 0.f, 0.f, 0.f};
            #pragma unroll
            for (int kk = 0; kk < 4; kk++) {
                h8 b = (_Float16)0.f;
                if (col < 4) b = *(const h8*)(Rb + (kk + 3) * 512 + boff);
                MFMA(ao, A2[0][kk], b);
            }
            if (lane < 4) {
                float* op = out + (size_t)(r0 + lane) * ostride + (size_t)(TSEQ - 2) * 3;
                op[0] = ao[0] + bl0; op[1] = ao[1] + bl1; op[2] = ao[2] + bl2;
            }
        }
        __syncthreads();
    }

    // ---- future (autoregressive), serial 3-barrier steps ----
    for (int t = TSEQ; t < steps; ++t) {
        _Float16* R = Sb[t & 1];
        _Float16* W = Sb[1 - (t & 1)];
        // pre: wave7 out(t-1) from W h2-region; feedback x(t) -> R x-slots
        if (wid == 7) {
            f4 ao = {0.f, 0.f, 0.f, 0.f};
            #pragma unroll
            for (int kk = 0; kk < 4; kk++) {
                h8 b = (_Float16)0.f;
                if (col < 4) b = *(const h8*)(W + (kk + 3) * 512 + boff);
                MFMA(ao, A2[0][kk], b);
            }
            if (lane < 4) {
                float o0 = ao[0] + bl0, o1 = ao[1] + bl1, o2 = ao[2] + bl2;
                float* op = out + (size_t)(r0 + lane) * ostride + (size_t)(t - 1) * 3;
                op[0] = o0; op[1] = o1; op[2] = o2;
                R[12 * 128 + lane * 8 + 5] = (_Float16)o0;
                R[12 * 128 + lane * 8 + 6] = (_Float16)o1;
                R[12 * 128 + lane * 8 + 7] = (_Float16)o2;
            }
        }
        __syncthreads();
        // A(t): read R kt0..3 -> h1(t) -> W h1-region
        if (wid < 7) {
            f4 a0 = {0.f,0.f,0.f,0.f}, a1 = a0, a2 = a0, a3 = a0;
            #pragma unroll
            for (int kt = 0; kt < 4; kt++) {
                h8 b = (_Float16)0.f;
                if (col < 4) b = *(const h8*)(R + kt * 512 + boff);
                MFMA(a0, A1[0][kt], b); MFMA(a1, A1[1][kt], b);
                MFMA(a2, A1[2][kt], b); MFMA(a3, A1[3][kt], b);
            }
            if (col < 4) {
                *(f4*)&zwA[wid][0][col][4 * q] = a0;
                *(f4*)&zwA[wid][1][col][4 * q] = a1;
                *(f4*)&zwA[wid][2][col][4 * q] = a2;
                *(f4*)&zwA[wid][3][col][4 * q] = a3;
            }
            float z0 = zwA[wid][0][r_ew][ul], z1 = zwA[wid][1][r_ew][ul];
            float z2 = zwA[wid][2][r_ew][ul], z3 = zwA[wid][3][r_ew][ul];
            float ig = sigm(z0), fg = sigm(z1), gg = tanhf_(z2), og = sigm(z3);
            c1 = fg * c1 + ig * gg;
            float h1v = og * tanhf_(c1);
            if (ewv) W[slot1] = (_Float16)h1v;
        }
        __syncthreads();
        // B(t): read W kt0..6 (h1(t), h2(t-1)) -> h2(t) -> R h2-region
        if (wid < 7) {
            f4 b0 = {0.f,0.f,0.f,0.f}, b1 = b0, b2 = b0, b3 = b0;
            #pragma unroll
            for (int kt = 0; kt < 7; kt++) {
                h8 b = (_Float16)0.f;
                if (col < 4) b = *(const h8*)(W + kt * 512 + boff);
                MFMA(b0, A2[0][kt], b); MFMA(b1, A2[1][kt], b);
                MFMA(b2, A2[2][kt], b); MFMA(b3, A2[3][kt], b);
            }
            if (col < 4) {
                *(f4*)&zwB[wid][0][col][4 * q] = b0;
                *(f4*)&zwB[wid][1][col][4 * q] = b1;
                *(f4*)&zwB[wid][2][col][4 * q] = b2;
                *(f4*)&zwB[wid][3][col][4 * q] = b3;
            }
            float z0 = zwB[wid][0][r_ew][ul], z1 = zwB[wid][1][r_ew][ul];
            float z2 = zwB[wid][2][r_ew][ul], z3 = zwB[wid][3][r_ew][ul];
            float ig = sigm(z0), fg = sigm(z1), gg = tanhf_(z2), og = sigm(z3);
            c2 = fg * c2 + ig * gg;
            float h2v = og * tanhf_(c2);
            if (ewv) R[slot2] = (_Float16)h2v;
        }
        __syncthreads();
    }

    // ---- epilogue: out(steps-1) from h2(steps-1) in Sb[1] ----
    if (wid == 7) {
        f4 ao = {0.f, 0.f, 0.f, 0.f};
        #pragma unroll
        for (int kk = 0; kk < 4; kk++) {
            h8 b = (_Float16)0.f;
            if (col < 4) b = *(const h8*)(&Sb[1][0] + (kk + 3) * 512 + boff);
            MFMA(ao, A2[0][kk], b);
        }
        if (lane < 4) {
            float* op = out + (size_t)(r0 + lane) * ostride + (size_t)(steps - 1) * 3;
            op[0] = ao[0] + bl0; op[1] = ao[1] + bl1; op[2] = ao[2] + bl2;
        }
    }
}

extern "C" void kernel_launch(void* const* d_in, const int* in_sizes, int n_in,
                              void* d_out, int out_size, void* d_ws, size_t ws_size,
                              hipStream_t stream) {
    const float* input = (const float*)d_in[0];
    const float* W_ih1 = (const float*)d_in[1];
    const float* W_hh1 = (const float*)d_in[2];
    const float* b_ih1 = (const float*)d_in[3];
    const float* b_hh1 = (const float*)d_in[4];
    const float* W_ih2 = (const float*)d_in[5];
    const float* W_hh2 = (const float*)d_in[6];
    const float* b_ih2 = (const float*)d_in[7];
    const float* b_hh2 = (const float*)d_in[8];
    const float* Wl    = (const float*)d_in[9];
    const float* bl    = (const float*)d_in[10];
    int steps = out_size / (BATCH * 3);       // 288
    _Float16* wsA = (_Float16*)d_ws;

    hipLaunchKernelGGL(prep_kernel, dim3(512), dim3(256), 0, stream,
                       W_ih1, W_hh1, b_ih1, b_hh1, W_ih2, W_hh2, b_ih2, b_hh2, Wl, wsA);
    hipLaunchKernelGGL(lstm_kernel, dim3(NBLK), dim3(NTHR), 0, stream,
                       input, wsA, bl, steps, (float*)d_out);
}

// Round 14
// 398.289 us; speedup vs baseline: 1.3374x; 1.0680x over previous
//
#include <hip/hip_runtime.h>
#include <hip/hip_bf16.h>

#define HID 101
#define BATCH 1024
#define RPB 4
#define NBLK 256
#define NTHR 512
#define TSEQ 256

#define A1SZ  (7*4*4*512)    // 57344 halfs
#define A2SZ  (7*4*7*512)    // 100352 halfs
#define A2OFF A1SZ
#define AOOFF (A1SZ + A2SZ)  // 157696
#define AOSZ  (4*512)

typedef _Float16 h8 __attribute__((ext_vector_type(8)));
typedef float f4 __attribute__((ext_vector_type(4)));

// ---------------------------------------------------------------------------
// Combined state vector (K=224, 7 k-tiles of 32):
//   k 0..100 : h1    k 101..103 : x    k 104 : one    k 112..212 : h2
// A1 (L1, kt0..3): k<101->W_hh1[g][k]; 101..103->W_ih1; 104->b1; else 0.
// A2 (L2, kt0..6): k<101->W_ih2[g][k]; 104->b2; 112..212->W_hh2[g][k-112]; else 0.
// AO (out head, frags for kt3..6): row j<3: k 112..212 -> Wl[j][k-112]; else 0.
// Fragment: lane l holds A[row=l&15][k = kt*32 + ((l>>4)&3)*8 + i], i=0..7.
// ---------------------------------------------------------------------------
__global__ void prep_kernel(const float* __restrict__ W_ih1, const float* __restrict__ W_hh1,
                            const float* __restrict__ b_ih1, const float* __restrict__ b_hh1,
                            const float* __restrict__ W_ih2, const float* __restrict__ W_hh2,
                            const float* __restrict__ b_ih2, const float* __restrict__ b_hh2,
                            const float* __restrict__ Wl, _Float16* __restrict__ wsA) {
    int idx = blockIdx.x * blockDim.x + threadIdx.x;
    int stride = gridDim.x * blockDim.x;
    for (int t = idx; t < A1SZ; t += stride) {
        int i = t & 7, lane = (t >> 3) & 63, kt = (t >> 9) & 3, tau = (t >> 11) & 3, w = t >> 13;
        int k = kt * 32 + ((lane >> 4) & 3) * 8 + i;
        int u = 16 * w + (lane & 15);
        float v = 0.f;
        if (u < HID) {
            int g = tau * HID + u;
            if (k < HID) v = W_hh1[g * HID + k];
            else if (k >= 101 && k <= 103) v = W_ih1[g * 3 + (k - 101)];
            else if (k == 104) v = b_ih1[g] + b_hh1[g];
        }
        wsA[t] = (_Float16)v;
    }
    for (int t = idx; t < A2SZ; t += stride) {
        int i = t & 7, lane = (t >> 3) & 63;
        int rem = t >> 9;
        int kt = rem % 7; rem /= 7;
        int tau = rem & 3, w = rem >> 2;
        int k = kt * 32 + ((lane >> 4) & 3) * 8 + i;
        int u = 16 * w + (lane & 15);
        float v = 0.f;
        if (u < HID) {
            int g = tau * HID + u;
            if (k < HID) v = W_ih2[g * HID + k];
            else if (k == 104) v = b_ih2[g] + b_hh2[g];
            else if (k >= 112 && k < 213) v = W_hh2[g * HID + (k - 112)];
        }
        wsA[A2OFF + t] = (_Float16)v;
    }
    for (int t = idx; t < AOSZ; t += stride) {
        int i = t & 7, lane = (t >> 3) & 63, kk = (t >> 9) & 3;
        int k = (kk + 3) * 32 + ((lane >> 4) & 3) * 8 + i;
        int j = lane & 15;
        float v = (j < 3 && k >= 112 && k < 213) ? Wl[j * HID + (k - 112)] : 0.f;
        wsA[AOOFF + t] = (_Float16)v;
    }
}

__device__ __forceinline__ float sigm(float z) {
    return __builtin_amdgcn_rcpf(1.f + __expf(-z));
}
__device__ __forceinline__ float tanhf_(float z) {
    return 1.f - 2.f * __builtin_amdgcn_rcpf(__expf(2.f * z) + 1.f);
}

#define MFMA(acc, a, b) acc = __builtin_amdgcn_mfma_f32_16x16x32_f16(a, b, acc, 0, 0, 0)

// ---------------------------------------------------------------------------
// persistent kernel: 256 blocks x 512 thr (8 waves).
// Teacher-forced pipeline, ONE barrier per timestep:
//   stage(t): A(t) [needs h1(t-1),x(t)] || B(t-1) [needs h1(t-1),h2(t-2)]
//             || wave7: out(t-2) + stage x(t+1).
// B-fragment ds_reads exec-masked to col<4 (cols 4-15 are zero padding):
// LDS pipe per stage drops ~4x (1KB -> 256B per b128 instruction).
// ---------------------------------------------------------------------------
__global__ __launch_bounds__(NTHR, 2) void lstm_kernel(
    const float* __restrict__ input, const _Float16* __restrict__ wsA,
    const float* __restrict__ bl, int steps, float* __restrict__ out)
{
    const int tid = threadIdx.x;
    const int wid = tid >> 6, lane = tid & 63;
    const int q = lane >> 4, col = lane & 15;
    const int r0 = blockIdx.x * RPB;
    const int ostride = steps * 3;

    __shared__ _Float16 Sb[2][3584];       // combined state buffers
    __shared__ float zwA[7][4][4][16];     // L1 z exchange
    __shared__ float zwB[7][4][4][16];     // L2 z exchange
    __shared__ _Float16 xpre[TSEQ * 12];   // staged inputs (f16)

    // --- weights: volatile loads -> execute once, stay register-resident ---
    h8 A1[4][4];
    h8 A2[4][7];
    if (wid < 7) {
        #pragma unroll
        for (int tau = 0; tau < 4; tau++) {
            #pragma unroll
            for (int kt = 0; kt < 4; kt++)
                A1[tau][kt] = *(const volatile h8*)(
                    wsA + ((size_t)((wid * 4 + tau) * 4 + kt) * 512 + lane * 8));
            #pragma unroll
            for (int kt = 0; kt < 7; kt++)
                A2[tau][kt] = *(const volatile h8*)(
                    wsA + (size_t)A2OFF + ((size_t)((wid * 4 + tau) * 7 + kt) * 512 + lane * 8));
        }
    } else {
        #pragma unroll
        for (int kt = 0; kt < 4; kt++)
            A2[0][kt] = *(const volatile h8*)(
                wsA + (size_t)AOOFF + ((size_t)(kt) * 512 + lane * 8));
    }
    const float bl0 = bl[0], bl1 = bl[1], bl2 = bl[2];

    // lane geometry
    const int r_ew = lane & 3, ul = lane >> 2;
    const int u = 16 * wid + ul;
    const bool ewv = (wid < 7) && (u < HID);
    const int slot1 = (u >> 3) * 128 + r_ew * 8 + (u & 7);           // h1 slot (k=u)
    const int slot2 = (14 + (u >> 3)) * 128 + r_ew * 8 + (u & 7);    // h2 slot (k=112+u)
    const int boff = q * 128 + col * 8;
    const int xr = lane / 3, xj = lane - 3 * xr;                     // wave7 lanes<12
    const int xoff = 12 * 128 + xr * 8 + 5 + xj;                     // x slot (k=101+xj)

    // ---- prologue ----
    for (int i2 = tid; i2 < 3584; i2 += NTHR) {
        Sb[0][i2] = (_Float16)0.f; Sb[1][i2] = (_Float16)0.f;
    }
    for (int g = tid; g < RPB * TSEQ * 3; g += NTHR) {
        int r = g / (TSEQ * 3), rem = g - r * (TSEQ * 3);
        int tt = rem / 3, j = rem - 3 * tt;
        xpre[tt * 12 + r * 3 + j] = (_Float16)input[(size_t)(r0 + r) * (TSEQ * 3) + rem];
    }
    __syncthreads();
    if (tid < 16) {   // bias-one slot k=104, both buffers
        Sb[0][13 * 128 + tid * 8] = (_Float16)1.0f;
        Sb[1][13 * 128 + tid * 8] = (_Float16)1.0f;
    }
    if (tid < 12) {  // x(0) -> S[0]
        int r = tid / 3, j = tid - 3 * (tid / 3);
        Sb[0][12 * 128 + r * 8 + 5 + j] = xpre[r * 3 + j];
    }
    float c1 = 0.f, c2 = 0.f;
    __syncthreads();

    // ---- teacher-forced pipeline: 1 barrier per step ----
    for (int t = 0; t < TSEQ; ++t) {
        _Float16* Rb = Sb[t & 1];
        _Float16* Wt = Sb[1 - (t & 1)];
        if (wid < 7) {
            // shared B-fragments (kt0..6), exec-masked to the 16 data-carrying lanes
            h8 bf0 = (_Float16)0.f, bf1 = bf0, bf2 = bf0, bf3 = bf0,
               bf4 = bf0, bf5 = bf0, bf6 = bf0;
            if (col < 4) {
                bf0 = *(const h8*)(Rb + 0 * 512 + boff);
                bf1 = *(const h8*)(Rb + 1 * 512 + boff);
                bf2 = *(const h8*)(Rb + 2 * 512 + boff);
                bf3 = *(const h8*)(Rb + 3 * 512 + boff);
                bf4 = *(const h8*)(Rb + 4 * 512 + boff);
                bf5 = *(const h8*)(Rb + 5 * 512 + boff);
                bf6 = *(const h8*)(Rb + 6 * 512 + boff);
            }
            // ---- A(t): L1 over kt0..3 ----
            f4 a0 = {0.f,0.f,0.f,0.f}, a1 = a0, a2 = a0, a3 = a0;
            MFMA(a0, A1[0][0], bf0); MFMA(a1, A1[1][0], bf0); MFMA(a2, A1[2][0], bf0); MFMA(a3, A1[3][0], bf0);
            MFMA(a0, A1[0][1], bf1); MFMA(a1, A1[1][1], bf1); MFMA(a2, A1[2][1], bf1); MFMA(a3, A1[3][1], bf1);
            MFMA(a0, A1[0][2], bf2); MFMA(a1, A1[1][2], bf2); MFMA(a2, A1[2][2], bf2); MFMA(a3, A1[3][2], bf2);
            MFMA(a0, A1[0][3], bf3); MFMA(a1, A1[1][3], bf3); MFMA(a2, A1[2][3], bf3); MFMA(a3, A1[3][3], bf3);
            if (col < 4) {
                *(f4*)&zwA[wid][0][col][4 * q] = a0;
                *(f4*)&zwA[wid][1][col][4 * q] = a1;
                *(f4*)&zwA[wid][2][col][4 * q] = a2;
                *(f4*)&zwA[wid][3][col][4 * q] = a3;
            }
            // ---- B(t-1): L2 over kt0..6 ----
            if (t >= 1) {
                f4 b0 = {0.f,0.f,0.f,0.f}, b1 = b0, b2 = b0, b3 = b0;
                MFMA(b0, A2[0][0], bf0); MFMA(b1, A2[1][0], bf0); MFMA(b2, A2[2][0], bf0); MFMA(b3, A2[3][0], bf0);
                MFMA(b0, A2[0][1], bf1); MFMA(b1, A2[1][1], bf1); MFMA(b2, A2[2][1], bf1); MFMA(b3, A2[3][1], bf1);
                MFMA(b0, A2[0][2], bf2); MFMA(b1, A2[1][2], bf2); MFMA(b2, A2[2][2], bf2); MFMA(b3, A2[3][2], bf2);
                MFMA(b0, A2[0][3], bf3); MFMA(b1, A2[1][3], bf3); MFMA(b2, A2[2][3], bf3); MFMA(b3, A2[3][3], bf3);
                MFMA(b0, A2[0][4], bf4); MFMA(b1, A2[1][4], bf4); MFMA(b2, A2[2][4], bf4); MFMA(b3, A2[3][4], bf4);
                MFMA(b0, A2[0][5], bf5); MFMA(b1, A2[1][5], bf5); MFMA(b2, A2[2][5], bf5); MFMA(b3, A2[3][5], bf5);
                MFMA(b0, A2[0][6], bf6); MFMA(b1, A2[1][6], bf6); MFMA(b2, A2[2][6], bf6); MFMA(b3, A2[3][6], bf6);
                if (col < 4) {
                    *(f4*)&zwB[wid][0][col][4 * q] = b0;
                    *(f4*)&zwB[wid][1][col][4 * q] = b1;
                    *(f4*)&zwB[wid][2][col][4 * q] = b2;
                    *(f4*)&zwB[wid][3][col][4 * q] = b3;
                }
            }
            // ---- ew A -> h1(t) -> Wt ----
            {
                float z0 = zwA[wid][0][r_ew][ul], z1 = zwA[wid][1][r_ew][ul];
                float z2 = zwA[wid][2][r_ew][ul], z3 = zwA[wid][3][r_ew][ul];
                float ig = sigm(z0), fg = sigm(z1), gg = tanhf_(z2), og = sigm(z3);
                c1 = fg * c1 + ig * gg;
                float h1v = og * tanhf_(c1);
                if (ewv) Wt[slot1] = (_Float16)h1v;
            }
            // ---- ew B -> h2(t-1) -> Wt ----
            if (t >= 1) {
                float z0 = zwB[wid][0][r_ew][ul], z1 = zwB[wid][1][r_ew][ul];
                float z2 = zwB[wid][2][r_ew][ul], z3 = zwB[wid][3][r_ew][ul];
                float ig = sigm(z0), fg = sigm(z1), gg = tanhf_(z2), og = sigm(z3);
                c2 = fg * c2 + ig * gg;
                float h2v = og * tanhf_(c2);
                if (ewv) Wt[slot2] = (_Float16)h2v;
            }
        } else {
            // ---- wave 7: out(t-2) from Rb h2-region; stage x(t+1) -> Wt ----
            if (t >= 2) {
                f4 ao = {0.f, 0.f, 0.f, 0.f};
                #pragma unroll
                for (int kk = 0; kk < 4; kk++) {
                    h8 b = (_Float16)0.f;
                    if (col < 4) b = *(const h8*)(Rb + (kk + 3) * 512 + boff);
                    MFMA(ao, A2[0][kk], b);
                }
                if (lane < 4) {
                    float* op = out + (size_t)(r0 + lane) * ostride + (size_t)(t - 2) * 3;
                    op[0] = ao[0] + bl0; op[1] = ao[1] + bl1; op[2] = ao[2] + bl2;
                }
            }
            if (t + 1 < TSEQ && lane < 12)
                Wt[xoff] = xpre[(t + 1) * 12 + xr * 3 + xj];
        }
        __syncthreads();
    }

    // ---- drain stage (t=TSEQ): B(T-1) + out(T-2). reads S[0], h2(T-1)->S[1] ----
    {
        _Float16* Rb = Sb[0];
        _Float16* Wt = Sb[1];
        if (wid < 7) {
            h8 bf0 = (_Float16)0.f, bf1 = bf0, bf2 = bf0, bf3 = bf0,
               bf4 = bf0, bf5 = bf0, bf6 = bf0;
            if (col < 4) {
                bf0 = *(const h8*)(Rb + 0 * 512 + boff);
                bf1 = *(const h8*)(Rb + 1 * 512 + boff);
                bf2 = *(const h8*)(Rb + 2 * 512 + boff);
                bf3 = *(const h8*)(Rb + 3 * 512 + boff);
                bf4 = *(const h8*)(Rb + 4 * 512 + boff);
                bf5 = *(const h8*)(Rb + 5 * 512 + boff);
                bf6 = *(const h8*)(Rb + 6 * 512 + boff);
            }
            f4 b0 = {0.f,0.f,0.f,0.f}, b1 = b0, b2 = b0, b3 = b0;
            MFMA(b0, A2[0][0], bf0); MFMA(b1, A2[1][0], bf0); MFMA(b2, A2[2][0], bf0); MFMA(b3, A2[3][0], bf0);
            MFMA(b0, A2[0][1], bf1); MFMA(b1, A2[1][1], bf1); MFMA(b2, A2[2][1], bf1); MFMA(b3, A2[3][1], bf1);
            MFMA(b0, A2[0][2], bf2); MFMA(b1, A2[1][2], bf2); MFMA(b2, A2[2][2], bf2); MFMA(b3, A2[3][2], bf2);
            MFMA(b0, A2[0][3], bf3); MFMA(b1, A2[1][3], bf3); MFMA(b2, A2[2][3], bf3); MFMA(b3, A2[3][3], bf3);
            MFMA(b0, A2[0][4], bf4); MFMA(b1, A2[1][4], bf4); MFMA(b2, A2[2][4], bf4); MFMA(b3, A2[3][4], bf4);
            MFMA(b0, A2[0][5], bf5); MFMA(b1, A2[1][5], bf5); MFMA(b2, A2[2][5], bf5); MFMA(b3, A2[3][5], bf5);
            MFMA(b0, A2[0][6], bf6); MFMA(b1, A2[1][6], bf6); MFMA(b2, A2[2][6], bf6); MFMA(b3, A2[3][6], bf6);
            if (col < 4) {
                *(f4*)&zwB[wid][0][col][4 * q] = b0;
                *(f4*)&zwB[wid][1][col][4 * q] = b1;
                *(f4*)&zwB[wid][2][col][4 * q] = b2;
                *(f4*)&zwB[wid][3][col][4 * q] = b3;
            }
            float z0 = zwB[wid][0][r_ew][ul], z1 = zwB[wid][1][r_ew][ul];
            float z2 = zwB[wid][2][r_ew][ul], z3 = zwB[wid][3][r_ew][ul];
            float ig = sigm(z0), fg = sigm(z1), gg = tanhf_(z2), og = sigm(z3);
            c2 = fg * c2 + ig * gg;
            float h2v = og * tanhf_(c2);
            if (ewv) Wt[slot2] = (_Float16)h2v;
        } else {
            f4 ao = {0.f, 0.f, 0.f, 0.f};
            #pragma unroll
            for (int kk = 0; kk < 4; kk++) {
                h8 b = (_Float16)0.f;
                if (col < 4) b = *(const h8*)(Rb + (kk + 3) * 512 + boff);
                MFMA(ao, A2[0][kk], b);
            }
            if (lane < 4) {
                float* op = out + (size_t)(r0 + lane) * ostride + (size_t)(TSEQ - 2) * 3;
                op[0] = ao[0] + bl0; op[1] = ao[1] + bl1; op[2] = ao[2] + bl2;
            }
        }
        __syncthreads();
    }

    // ---- future (autoregressive), serial 3-barrier steps ----
    for (int t = TSEQ; t < steps; ++t) {
        _Float16* R = Sb[t & 1];
        _Float16* W = Sb[1 - (t & 1)];
        // pre: wave7 out(t-1) from W h2-region; feedback x(t) -> R x-slots
        if (wid == 7) {
            f4 ao = {0.f, 0.f, 0.f, 0.f};
            #pragma unroll
            for (int kk = 0; kk < 4; kk++) {
                h8 b = (_Float16)0.f;
                if (col < 4) b = *(const h8*)(W + (kk + 3) * 512 + boff);
                MFMA(ao, A2[0][kk], b);
            }
            if (lane < 4) {
                float o0 = ao[0] + bl0, o1 = ao[1] + bl1, o2 = ao[2] + bl2;
                float* op = out + (size_t)(r0 + lane) * ostride + (size_t)(t - 1) * 3;
                op[0] = o0; op[1] = o1; op[2] = o2;
                R[12 * 128 + lane * 8 + 5] = (_Float16)o0;
                R[12 * 128 + lane * 8 + 6] = (_Float16)o1;
                R[12 * 128 + lane * 8 + 7] = (_Float16)o2;
            }
        }
        __syncthreads();
        // A(t): read R kt0..3 -> h1(t) -> W h1-region
        if (wid < 7) {
            f4 a0 = {0.f,0.f,0.f,0.f}, a1 = a0, a2 = a0, a3 = a0;
            #pragma unroll
            for (int kt = 0; kt < 4; kt++) {
                h8 b = (_Float16)0.f;
                if (col < 4) b = *(const h8*)(R + kt * 512 + boff);
                MFMA(a0, A1[0][kt], b); MFMA(a1, A1[1][kt], b);
                MFMA(a2, A1[2][kt], b); MFMA(a3, A1[3][kt], b);
            }
            if (col < 4) {
                *(f4*)&zwA[wid][0][col][4 * q] = a0;
                *(f4*)&zwA[wid][1][col][4 * q] = a1;
                *(f4*)&zwA[wid][2][col][4 * q] = a2;
                *(f4*)&zwA[wid][3][col][4 * q] = a3;
            }
            float z0 = zwA[wid][0][r_ew][ul], z1 = zwA[wid][1][r_ew][ul];
            float z2 = zwA[wid][2][r_ew][ul], z3 = zwA[wid][3][r_ew][ul];
            float ig = sigm(z0), fg = sigm(z1), gg = tanhf_(z2), og = sigm(z3);
            c1 = fg * c1 + ig * gg;
            float h1v = og * tanhf_(c1);
            if (ewv) W[slot1] = (_Float16)h1v;
        }
        __syncthreads();
        // B(t): read W kt0..6 (h1(t), h2(t-1)) -> h2(t) -> R h2-region
        if (wid < 7) {
            f4 b0 = {0.f,0.f,0.f,0.f}, b1 = b0, b2 = b0, b3 = b0;
            #pragma unroll
            for (int kt = 0; kt < 7; kt++) {
                h8 b = (_Float16)0.f;
                if (col < 4) b = *(const h8*)(W + kt * 512 + boff);
                MFMA(b0, A2[0][kt], b); MFMA(b1, A2[1][kt], b);
                MFMA(b2, A2[2][kt], b); MFMA(b3, A2[3][kt], b);
            }
            if (col < 4) {
                *(f4*)&zwB[wid][0][col][4 * q] = b0;
                *(f4*)&zwB[wid][1][col][4 * q] = b1;
                *(f4*)&zwB[wid][2][col][4 * q] = b2;
                *(f4*)&zwB[wid][3][col][4 * q] = b3;
            }
            float z0 = zwB[wid][0][r_ew][ul], z1 = zwB[wid][1][r_ew][ul];
            float z2 = zwB[wid][2][r_ew][ul], z3 = zwB[wid][3][r_ew][ul];
            float ig = sigm(z0), fg = sigm(z1), gg = tanhf_(z2), og = sigm(z3);
            c2 = fg * c2 + ig * gg;
            float h2v = og * tanhf_(c2);
            if (ewv) R[slot2] = (_Float16)h2v;
        }
        __syncthreads();
    }

    // ---- epilogue: out(steps-1) from h2(steps-1) in Sb[1] ----
    if (wid == 7) {
        f4 ao = {0.f, 0.f, 0.f, 0.f};
        #pragma unroll
        for (int kk = 0; kk < 4; kk++) {
            h8 b = (_Float16)0.f;
            if (col < 4) b = *(const h8*)(&Sb[1][0] + (kk + 3) * 512 + boff);
            MFMA(ao, A2[0][kk], b);
        }
        if (lane < 4) {
            float* op = out + (size_t)(r0 + lane) * ostride + (size_t)(steps - 1) * 3;
            op[0] = ao[0] + bl0; op[1] = ao[1] + bl1; op[2] = ao[2] + bl2;
        }
    }
}

extern "C" void kernel_launch(void* const* d_in, const int* in_sizes, int n_in,
                              void* d_out, int out_size, void* d_ws, size_t ws_size,
                              hipStream_t stream) {
    const float* input = (const float*)d_in[0];
    const float* W_ih1 = (const float*)d_in[1];
    const float* W_hh1 = (const float*)d_in[2];
    const float* b_ih1 = (const float*)d_in[3];
    const float* b_hh1 = (const float*)d_in[4];
    const float* W_ih2 = (const float*)d_in[5];
    const float* W_hh2 = (const float*)d_in[6];
    const float* b_ih2 = (const float*)d_in[7];
    const float* b_hh2 = (const float*)d_in[8];
    const float* Wl    = (const float*)d_in[9];
    const float* bl    = (const float*)d_in[10];
    int steps = out_size / (BATCH * 3);       // 288
    _Float16* wsA = (_Float16*)d_ws;

    hipLaunchKernelGGL(prep_kernel, dim3(512), dim3(256), 0, stream,
                       W_ih1, W_hh1, b_ih1, b_hh1, W_ih2, W_hh2, b_ih2, b_hh2, Wl, wsA);
    hipLaunchKernelGGL(lstm_kernel, dim3(NBLK), dim3(NTHR), 0, stream,
                       input, wsA, bl, steps, (float*)d_out);
}